// Round 8
// baseline (16.976 us; speedup 1.0000x reference)
//
#include <hip/hip_runtime.h>
#include <hip/hip_bf16.h>
#include <cstdint>
#include <climits>

#define HW 112
#define NPIX (HW*HW)   // 12544
#define NB 2
#define NC 4
#define HALF_ROWS 56
#define HD_BLKS 24     // 12 (b,dir,class) x 2 half-planes

// ws layout:
//   +0:      packed masks  uint64_t[12 masks][112 rows][2 words]   (21504 B)
//   +21504:  g^2 planes    uint16_t[12 planes][12544]              (301056 B)
//   +322560: S[24] half-plane sums | +322656: Cc[24] counts
//   +322752: unsigned counter (zeroed by prep blk0 each launch)
// mask id = b*6 + m, m=0..2 -> A(j=m+1) (argmax==j), m=3..5 -> B(j=m-2) (label==1)

__global__ __launch_bounds__(128) void prep_kernel(
    const float* __restrict__ pred, const int* __restrict__ labels,
    unsigned long long* __restrict__ masks, unsigned short* __restrict__ gsqbuf,
    unsigned* __restrict__ counter)
{
  int blk = blockIdx.x;
  int b = blk / HW, r = blk % HW;
  int tid = threadIdx.x;
  int lane = tid & 63, wave = tid >> 6;
  int c = tid;

  if (blk == 0 && tid == 0) *counter = 0;   // replay-safe: reset every launch

  int cls = 255;
  if (c < HW) {
    const float* p0 = pred + ((size_t)(b*NC)*HW + r)*HW + c;
    float best = p0[0]; cls = 0;
    #pragma unroll
    for (int ch = 1; ch < NC; ch++) {
      float v = p0[(size_t)ch*NPIX];
      if (v > best) { best = v; cls = ch; }   // strict > : argmax tie-break
    }
  }

  __shared__ unsigned long long sm[6][2];
  #pragma unroll
  for (int m = 0; m < 3; m++) {
    bool p = (c < HW) && (cls == m + 1);
    unsigned long long bal = __ballot(p);
    if (lane == 0) sm[m][wave] = bal;
  }
  #pragma unroll
  for (int m = 0; m < 3; m++) {
    int lab = (c < HW) ? labels[((size_t)(b*NC + (m+1))*HW + r)*HW + c] : 0;
    bool p = (c < HW) && (lab == 1);
    unsigned long long bal = __ballot(p);
    if (lane == 0) sm[3 + m][wave] = bal;
  }
  __syncthreads();

  if (tid < 12) {
    int m = tid >> 1, w = tid & 1;
    masks[((size_t)(b*6 + m)*HW + r)*2 + w] = sm[m][w];
  }

  // phase 1: horizontal nearest-set-pixel distance, O(1)/pixel via clz/ffs
  for (int item = tid; item < 6*HW; item += 128) {
    int m = item / HW, cc = item % HW;
    unsigned long long lo = sm[m][0], hi = sm[m][1];
    int left, right;
    if (cc < 64) {
      unsigned long long wl = lo & ((2ull << cc) - 1);
      left = wl ? 63 - __clzll(wl) : -1000;
      unsigned long long wr = lo & ~((1ull << cc) - 1);
      right = wr ? __ffsll(wr) - 1 : (hi ? 64 + __ffsll(hi) - 1 : 1000);
    } else {
      int cl = cc - 64;
      unsigned long long wl = hi & ((2ull << cl) - 1);
      left = wl ? 64 + 63 - __clzll(wl) : (lo ? 63 - __clzll(lo) : -1000);
      unsigned long long wr = hi & ~((1ull << cl) - 1);
      right = wr ? 64 + __ffsll(wr) - 1 : 1000;
    }
    int gv = min(min(cc - left, right - cc), 255);  // 255 sentinel: empty row
    gsqbuf[(size_t)(b*6 + m)*NPIX + r*HW + cc] = (unsigned short)(gv*gv);
  }
}

__device__ __forceinline__ int g2row(const unsigned short* __restrict__ g2p, int row) {
  return (row >= 0 && row < HW) ? (int)g2p[(size_t)row*HW] : 0x7fff;
}

// 24 blocks x 1024 threads: one per (pair-dir, half-plane). 896 active threads
// = 8 row-groups x 112 cols, 7 rows each via sliding 5-row register window;
// early-exit d<=2 + rare tail (exact branch-and-bound, proven R7).
// Last block to finish (counter) finalizes the 18 outputs inline: publish via
// device-scope atomicExch + fence, RMW-read pattern proven in R5.
__global__ __launch_bounds__(1024) void hd_kernel(
    const unsigned long long* __restrict__ masks,
    const unsigned short* __restrict__ gsqbuf,
    float* __restrict__ S, float* __restrict__ Cc,
    unsigned* __restrict__ counter, float* __restrict__ out)
{
  int blk = blockIdx.x;
  int pd = blk >> 1, half = blk & 1;
  int b = pd / 6, k = pd % 6;
  // k<3: fwd for j=k+1 (src = B/label g2-plane, tgt = A/argmax mask); k>=3: swapped
  int src = b*6 + (k + 3) % 6;
  int tid = threadIdx.x, lane = tid & 63, wv = tid >> 6;
  int rg = tid / HW, c = tid % HW;

  float sum = 0.f, cf = 0.f;
  if (rg < 8) {
    const unsigned short* g2p = gsqbuf + (size_t)src*NPIX + c;
    int rbase = half*HALF_ROWS + rg*7;
    int vm2 = g2row(g2p, rbase - 2), vm1 = g2row(g2p, rbase - 1);
    int v0  = g2row(g2p, rbase),     vp1 = g2row(g2p, rbase + 1);
    int vp2 = g2row(g2p, rbase + 2);
    #pragma unroll 7
    for (int i = 0; i < 7; i++) {
      int r = rbase + i;
      int best = v0;
      best = min(best, 1 + min(vm1, vp1));
      best = min(best, 4 + min(vm2, vp2));
      if (best > 9) {                         // rare exact tail
        for (int d = 3; d < HW; d++) {
          int dd = d*d;
          if (dd >= best) break;
          int ru = r - d, rd = r + d;
          if (ru >= 0)  best = min(best, dd + (int)g2p[(size_t)ru*HW]);
          if (rd < HW)  best = min(best, dd + (int)g2p[(size_t)rd*HW]);
        }
      }
      unsigned long long wm = masks[((size_t)pd*HW + r)*2 + (c >> 6)];
      if ((wm >> (c & 63)) & 1ull) { sum += sqrtf((float)best); cf += 1.f; }
      vm2 = vm1; vm1 = v0; v0 = vp1; vp1 = vp2; vp2 = g2row(g2p, r + 3);
    }
  }

  #pragma unroll
  for (int off = 32; off; off >>= 1) {
    sum += __shfl_down(sum, off, 64);
    cf  += __shfl_down(cf, off, 64);
  }
  __shared__ float red[32];
  __shared__ int isLast;
  if (lane == 0) { red[wv*2] = sum; red[wv*2 + 1] = cf; }
  __syncthreads();
  if (tid == 0) {
    float Sv = 0.f, Cv = 0.f;
    #pragma unroll
    for (int w = 0; w < 16; w++) { Sv += red[w*2]; Cv += red[w*2 + 1]; }
    atomicExch(&S[blk], Sv);                 // device-scope publish (R5-proven)
    atomicExch(&Cc[blk], Cv);
    __threadfence();
    unsigned old = atomicAdd(counter, 1u);
    isLast = (old == HD_BLKS - 1) ? 1 : 0;
  }
  __syncthreads();

  if (isLast) {
    __shared__ float fs[HD_BLKS], fc[HD_BLKS], sacc[24];
    if (tid < HD_BLKS) {                     // coherent RMW read-back
      fs[tid] = atomicAdd(&S[tid], 0.0f);
      fc[tid] = atomicAdd(&Cc[tid], 0.0f);
    }
    __syncthreads();
    if (tid < 12) {
      sacc[tid]      = fs[tid*2] + fs[tid*2 + 1];
      sacc[12 + tid] = fc[tid*2] + fc[tid*2 + 1];
    }
    __syncthreads();
    if (tid == 0) {
      float mhd[6], fhd[6], rhd[6];
      for (int i = 0; i < 6; i++) { mhd[i] = 0.f; fhd[i] = 0.f; rhd[i] = 0.f; }
      for (int bb = 0; bb < 2; bb++)
        for (int j = 1; j < 4; j++) {
          int pf = bb*6 + (j - 1);
          int pr = bb*6 + 3 + (j - 1);
          float fwd = sacc[pf] / sacc[12 + pf];
          float rev = sacc[pr] / sacc[12 + pr];
          fhd[j] += fwd; rhd[j] += rev; mhd[j] += fmaxf(fwd, rev);
        }
      float* arrs[3] = { mhd, fhd, rhd };
      for (int a = 0; a < 3; a++) {
        float* x = arrs[a];
        for (int i = 0; i < 4; i++) x[i] *= 0.5f;          // /N
        x[4] = (x[0] + x[1] + x[2] + x[3]) * 0.25f;        // mean(x[:C])
        x[5] = (x[1] + x[2] + x[3]) * (1.f / 3.f);         // mean(x[1:C])
        for (int i = 0; i < 6; i++) out[a*6 + i] = x[i];
      }
    }
  }
}

extern "C" void kernel_launch(void* const* d_in, const int* in_sizes, int n_in,
                              void* d_out, int out_size, void* d_ws, size_t ws_size,
                              hipStream_t stream) {
  const float* pred = (const float*)d_in[0];
  const int* labels = (const int*)d_in[1];
  float* out = (float*)d_out;

  unsigned long long* masks = (unsigned long long*)d_ws;
  unsigned short* gsqbuf = (unsigned short*)((char*)d_ws + 21504);
  float* S  = (float*)((char*)d_ws + 322560);
  float* Cc = (float*)((char*)d_ws + 322656);
  unsigned* counter = (unsigned*)((char*)d_ws + 322752);

  prep_kernel<<<NB*HW, 128, 0, stream>>>(pred, labels, masks, gsqbuf, counter);
  hd_kernel<<<HD_BLKS, 1024, 0, stream>>>(masks, gsqbuf, S, Cc, counter, out);
}